// Round 4
// baseline (315.646 us; speedup 1.0000x reference)
//
#include <hip/hip_runtime.h>
#include <hip/hip_bf16.h>
#include <cstdint>

// KANLinear fused as ONE bf16 GEMM, K = 1024*8 (spline basis) + 1024 (silu) = 9216.
//   A[b, 8i+k]   = basis_k(x[b,i]);  A[b, 8192+i] = silu(x[b,i])
//   W[o, 8i+k]   = spline_weight[o,i,k];  W[o, 8192+i] = base_weight[o,i]
// out = A @ W^T  (M=8192, N=1024, K=9216), fp32 in/out, bf16 MFMA internal.
//
// R13 = R12 (128x256, ring-3, 2 blocks/CU, counted vmcnt) + k-octet XOR
// swizzle. Desk arithmetic on R12: LDS-read floor (128 KB/CU/K-step =
// 1024 cy) == MFMA floor (1024 cy); R11 measured ~8-way bank conflicts
// (+33% LDS) on the frag-read pattern row*64+q*16 (even rows share one
// bank quad) -> conflicts would make LDS the binding pipe. Swizzle:
//   stage: thread (srow,sq) loads global k-octet  sq ^ ((srow>>1)&3)
//   read : frag slot                              q  ^ ((r16 >>1)&3)
// Involution (m201/m173 pattern, rule 21: linear LDS dest + pre-swizzled
// source + swizzled read). (row>>1)&3 == (r16>>1)&3 for all tm/wm shifts
// (multiples of 16) -> swizzle folds into the per-lane frag base, zero
// inner-loop cost. Conflicts drop to 2-way (free, m136).
// Schedule recap (R12):
//   - 128x256 tile -> 64x4 = 256 WGs, NO split-K, NO reduce pass
//   - ring-of-3 at BK=32 = 72 KB LDS -> 2 blocks/CU = 16 waves/CU
//   - wave tile 64x64 (2x4 waves), __launch_bounds__(512,4)
//   - counted vmcnt(6) at tile boundary (never 0 in-loop), raw s_barrier,
//     sched_barrier(0) fences, setprio(1) around MFMA, clamped tail
//   - XCD swizzle: xcd = linear%8 owns 8 rowBands x 4 colBands.

typedef short s16x8 __attribute__((ext_vector_type(8)));   // 8 bf16 in 4 VGPRs
typedef float f32x4 __attribute__((ext_vector_type(4)));

#define GK 9216
#define GN 1024
#define GI 1024
#define GM 8192

#define BK 32
#define NT 288               // GK/BK

#define BS_BLK 32768   // basis+silu: 8192*1024 threads (1 per x)
#define RP_BLK 4608    // repack   : 1024*1152 threads (8 cols each)

__device__ __forceinline__ void cp16(const __hip_bfloat16* g, __hip_bfloat16* l) {
  __builtin_amdgcn_global_load_lds((const __attribute__((address_space(1))) void*)g,
                                   (__attribute__((address_space(3))) void*)l, 16, 0, 0);
}

__device__ __forceinline__ uint32_t bfbits(float f) {   // RTNE bf16 bits, SSA only
  __hip_bfloat16 h = __float2bfloat16(f);
  unsigned short us;
  __builtin_memcpy(&us, &h, 2);
  return (uint32_t)us;
}

__device__ __forceinline__ void basis4(float xv, int& jj, float& w0, float& w1,
                                       float& w2, float& w3) {
  float t = fminf(1.f, fmaxf(-1.f, xv));
  float us = (t + 1.f) * 2.5f;          // (t - grid[3]) / h, grid[3]=-1, h=0.4
  int j = (int)us;
  if (j > 4) j = 4;                     // t==1.0 edge: matches reference exactly
  float u = us - (float)j;
  float u2 = u * u, u3 = u2 * u;
  float om = 1.f - u;
  jj = j;
  w0 = om * om * om * (1.f / 6.f);
  w1 = (3.f * u3 - 6.f * u2 + 4.f) * (1.f / 6.f);
  w2 = (-3.f * u3 + 3.f * u2 + 3.f * u + 1.f) * (1.f / 6.f);
  w3 = u3 * (1.f / 6.f);
}

// --- ONE dispatch: basis+silu (1 thread/x) + weight repack -----------------
__global__ void kan_prep_all(const float* __restrict__ x,
                             const float* __restrict__ baseW,
                             const float* __restrict__ splineW,
                             __hip_bfloat16* __restrict__ W2,
                             __hip_bfloat16* __restrict__ A) {
  int bid = blockIdx.x;
  if (bid < BS_BLK) {
    int t = bid * 256 + threadIdx.x;        // [0, 8192*1024)
    int b = t >> 10, i = t & 1023;
    float xv = x[t];

    // silu -> A[b, 8192+i], 2 B coalesced store
    float sl = xv / (1.f + __expf(-xv));
    A[(size_t)b * GK + 8192 + i] = __float2bfloat16(sl);

    // basis -> A[b, 8i..8i+7]: funnel-shift packed weights into window jj,
    // one dense 16 B store per lane (stride-16 across the wave)
    int jj; float w0, w1, w2, w3;
    basis4(xv, jj, w0, w1, w2, w3);
    uint64_t W64 = (uint64_t)(bfbits(w0) | (bfbits(w1) << 16)) |
                   ((uint64_t)(bfbits(w2) | (bfbits(w3) << 16)) << 32);
    int sh = jj * 16;                                  // 0,16,32,48,64
    uint64_t lo = (jj < 4) ? (W64 << sh) : 0ull;       // guard UB at sh=64
    uint64_t hi = (jj == 0) ? 0ull : (W64 >> (64 - sh));
    uint4 pk;
    pk.x = (uint32_t)lo;  pk.y = (uint32_t)(lo >> 32);
    pk.z = (uint32_t)hi;  pk.w = (uint32_t)(hi >> 32);
    *(uint4*)(A + (size_t)b * GK + (size_t)i * 8) = pk;
  } else {
    // repack: thread handles 8 cols (32 B fp32 in, 16 B bf16 out)
    int t = (bid - BS_BLK) * 256 + threadIdx.x;   // [0, 1024*1152)
    int o = t / 1152;
    int c = (t - o * 1152) * 8;
    const float* src = (c < 8192) ? (splineW + (size_t)o * 8192 + c)
                                  : (baseW + (size_t)o * GI + (c - 8192));
    float4 v0 = ((const float4*)src)[0];
    float4 v1 = ((const float4*)src)[1];
    uint4 pk;
    pk.x = bfbits(v0.x) | (bfbits(v0.y) << 16);
    pk.y = bfbits(v0.z) | (bfbits(v0.w) << 16);
    pk.z = bfbits(v1.x) | (bfbits(v1.y) << 16);
    pk.w = bfbits(v1.z) | (bfbits(v1.w) << 16);
    *(uint4*)(W2 + (size_t)o * GK + c) = pk;
  }
}

// --- R13 GEMM: 128x256 tile, BK=32, ring-3 (72 KB), 2 blocks/CU, swizzle ---
__global__ __launch_bounds__(512, 4) void kan_gemm_bc(
    const __hip_bfloat16* __restrict__ A,   // (8192, 9216) bf16
    const __hip_bfloat16* __restrict__ B,   // (1024, 9216) bf16
    float* __restrict__ C) {                // (8192, 1024) fp32
  __shared__ __align__(16) __hip_bfloat16 As[3][128 * BK];   // 3 x 8 KB
  __shared__ __align__(16) __hip_bfloat16 Bs[3][256 * BK];   // 3 x 16 KB
  const int tid = threadIdx.x;
  const int lane = tid & 63;
  const int wave = tid >> 6;                 // 0..7
  const int wm = wave >> 2, wn = wave & 3;   // 2x4 waves, 64x64 out each

  // XCD swizzle over exactly 256 WGs: xcd = linear%8 owns 32 consecutive c's
  // = 8 rowBands x 4 colBands -> A panels L2-shared x4 within the XCD.
  const int linear = blockIdx.y * 4 + blockIdx.x;       // 0..255
  const int c = (linear & 7) * 32 + (linear >> 3);
  const int colBand = c & 3;                 // 0..3
  const int rowBand = c >> 2;                // 0..63
  const int blockRow = rowBand * 128;
  const int blockCol = colBand * 256;

  // staging: per cp16, 512 lanes x 16 B = 8 KB = 128 rows x 32 k, linear LDS.
  // k-octet XOR swizzle on the GLOBAL side: thread (srow,sq) loads octet
  // sq ^ ((srow>>1)&3). Same 64 B per 4-lane group -> coalescing unchanged.
  const int srow = tid >> 2;                 // 0..127
  const int sq = tid & 3;
  const int ssw = sq ^ ((srow >> 1) & 3);    // swizzled source octet
  const __hip_bfloat16* aSrc = A + (size_t)(blockRow + srow) * GK + ssw * 8;
  const __hip_bfloat16* bSrc = B + (size_t)(blockCol + srow) * GK + ssw * 8;
  const int ldsOff = wave * 512;             // wave-uniform; HW adds lane*16 B

  // STAGE = 3 cp16: A tile 8 KB (1), B tile 16 KB (2: rows 0-127, 128-255)
  // ((srow+128)>>1)&3 == (srow>>1)&3, so one swizzle works for both halves.
#define STAGE(T, BUF)                                             \
  do {                                                            \
    const __hip_bfloat16* ga = aSrc + (T) * BK;                   \
    const __hip_bfloat16* gb = bSrc + (T) * BK;                   \
    cp16(ga, As[BUF] + ldsOff);                                   \
    cp16(gb, Bs[BUF] + ldsOff);                                   \
    cp16(gb + 128 * GK, Bs[BUF] + ldsOff + 4096);                 \
  } while (0)

  const int q = lane >> 4, r16 = lane & 15;
  // frag read slot = q ^ ((row>>1)&3); row = w*64 + r16 + tm*16 and 64/16
  // are ==0 mod 4 after >>1, so the swizzle is the per-lane constant below.
  const int qs = q ^ ((r16 >> 1) & 3);
  const int aBase = (wm * 64 + r16) * 4 + qs;   // s16x8 index; +tm*64
  const int bBase = (wn * 64 + r16) * 4 + qs;   // +tn*64

  f32x4 acc[4][4] = {};

  // prologue: 3 tiles in flight (9 loads), issue-order pinned per tile so
  // vmcnt(6) really confirms tile 0; then drain to 6.
  STAGE(0, 0);
  __builtin_amdgcn_sched_barrier(0);
  STAGE(1, 1);
  __builtin_amdgcn_sched_barrier(0);
  STAGE(2, 2);
  __builtin_amdgcn_sched_barrier(0);
  asm volatile("s_waitcnt vmcnt(6)" ::: "memory");
  __builtin_amdgcn_sched_barrier(0);
  __builtin_amdgcn_s_barrier();

  for (int t3 = 0; t3 < NT / 3; ++t3) {
#pragma unroll
    for (int u = 0; u < 3; ++u) {
      const int t = t3 * 3 + u;
      // tail guard: last 3 iters restage tile 0 (never read again) to keep
      // the vmcnt count identical without reading past the buffer.
      const int tp = (t + 3 < NT) ? (t + 3) : 0;
      __builtin_amdgcn_sched_barrier(0);
      // frag reads of buf u (tile t) — landed per prev iter's vmcnt+barrier
      const s16x8* Af = (const s16x8*)As[u];
      const s16x8* Bf = (const s16x8*)Bs[u];
      s16x8 af[4], bfg[4];
#pragma unroll
      for (int tm = 0; tm < 4; ++tm) af[tm] = Af[aBase + tm * 64];
#pragma unroll
      for (int tn = 0; tn < 4; ++tn) bfg[tn] = Bf[bBase + tn * 64];
      asm volatile("s_waitcnt lgkmcnt(0)" ::: "memory");
      __builtin_amdgcn_sched_barrier(0);
      __builtin_amdgcn_s_barrier();     // ALL waves done reading buf u
      __builtin_amdgcn_sched_barrier(0);
      STAGE(tp, u);                     // overwrite now safe (WAR ordered)
      __builtin_amdgcn_sched_barrier(0);
      __builtin_amdgcn_s_setprio(1);
#pragma unroll
      for (int tm = 0; tm < 4; ++tm)
#pragma unroll
        for (int tn = 0; tn < 4; ++tn)
          acc[tm][tn] = __builtin_amdgcn_mfma_f32_16x16x32_bf16(
              af[tm], bfg[tn], acc[tm][tn], 0, 0, 0);
      __builtin_amdgcn_s_setprio(0);
      // counted: 6 newest loads (tiles t+2, t+3) stay in flight; tile t+1
      // (oldest 3 of the 9) is confirmed. Never drain to 0 in the loop.
      asm volatile("s_waitcnt vmcnt(6)" ::: "memory");
      __builtin_amdgcn_sched_barrier(0);
      __builtin_amdgcn_s_barrier();
    }
  }
  // drain the tail prefetches before LDS goes away
  asm volatile("s_waitcnt vmcnt(0)" ::: "memory");

  // C/D layout: col = lane&15, row = (lane>>4)*4 + reg  [m89-verified]
  const int cRow0 = blockRow + wm * 64 + q * 4;
  const int cCol0 = blockCol + wn * 64 + r16;
#pragma unroll
  for (int tm = 0; tm < 4; ++tm)
#pragma unroll
    for (int tn = 0; tn < 4; ++tn) {
      int col = cCol0 + tn * 16;
      size_t base = (size_t)(cRow0 + tm * 16) * GN + col;
#pragma unroll
      for (int r = 0; r < 4; ++r)
        C[base + (size_t)r * GN] = acc[tm][tn][r];
    }
#undef STAGE
}

// --- emergency fallback if ws_size is too small ----------------------------
__global__ void kan_naive(const float* __restrict__ x,
                          const float* __restrict__ bw,
                          const float* __restrict__ sw,
                          float* __restrict__ out) {
  int o = blockIdx.x * 256 + threadIdx.x;
  int b = blockIdx.y;
  float acc = 0.f;
  for (int i = 0; i < GI; ++i) {
    float xv = x[(size_t)b * GI + i];
    float sl = xv / (1.f + __expf(-xv));
    acc += sl * bw[(size_t)o * GI + i];
    int jj; float w0, w1, w2, w3;
    basis4(xv, jj, w0, w1, w2, w3);
    const float* swr = sw + ((size_t)o * GI + i) * 8 + jj;
    acc += w0 * swr[0] + w1 * swr[1] + w2 * swr[2] + w3 * swr[3];
  }
  out[(size_t)b * GN + o] = acc;
}

extern "C" void kernel_launch(void* const* d_in, const int* in_sizes, int n_in,
                              void* d_out, int out_size, void* d_ws, size_t ws_size,
                              hipStream_t stream) {
  const float* x  = (const float*)d_in[0];   // (8192, 1024) fp32
  const float* bw = (const float*)d_in[1];   // (1024, 1024) fp32
  const float* sw = (const float*)d_in[2];   // (1024, 1024, 8) fp32
  float* out = (float*)d_out;                // (8192, 1024) fp32

  const size_t wBytes = (size_t)GK * GN * 2;   // 18.9 MB repacked weights
  const size_t aBytes = (size_t)GM * GK * 2;   // 151 MB activations

  if (ws_size < wBytes + aBytes) {
    kan_naive<<<dim3(GN / 256, GM), 256, 0, stream>>>(x, bw, sw, out);
    return;
  }

  __hip_bfloat16* W2 = (__hip_bfloat16*)d_ws;
  __hip_bfloat16* Abuf = W2 + (size_t)GK * GN;       // 16B-aligned

  kan_prep_all<<<BS_BLK + RP_BLK, 256, 0, stream>>>(x, bw, sw, W2, Abuf);
  kan_gemm_bc<<<dim3(4, 64), 512, 0, stream>>>(Abuf, W2, out);
}

// Round 5
// 295.874 us; speedup vs baseline: 1.0668x; 1.0668x over previous
//
#include <hip/hip_runtime.h>
#include <hip/hip_bf16.h>
#include <cstdint>

// KANLinear fused as ONE bf16 GEMM, K = 1024*8 (spline basis) + 1024 (silu) = 9216.
//   A[b, 8i+k]   = basis_k(x[b,i]);  A[b, 8192+i] = silu(x[b,i])
//   W[o, 8i+k]   = spline_weight[o,i,k];  W[o, 8192+i] = base_weight[o,i]
// out = A @ W^T  (M=8192, N=1024, K=9216), fp32 in/out, bf16 MFMA internal.
//
// R14: R13 post-mortem — swizzle killed bank conflicts (1.4e7 -> 0) but dur
// went 167->197: grid=256 WGs on 256 CUs means 1 block/CU BY CONSTRUCTION,
// so the lockstep barrier chain (ds_read latency + lgkm + 3 barriers +
// vmcnt) is fully exposed (1642 cy/K-step vs 620 cy MFMA floor). Fix:
//   - 128x128 tile, 256 threads (4 waves 2x2, 64x64 wave tile keeps the
//     16-MFMA/8-read density) -> grid 64x8 = 512 WGs = 2 blocks/CU; the
//     two blocks have INDEPENDENT barriers and hide each other's stalls
//   - ring-3 at BK=32 = 48 KB LDS -> 2 blocks/CU = 96 KB; lb(256,2)
//   - counted vmcnt ring unchanged: 4 cp16/STAGE, 3 tiles in flight (12
//     loads), boundary vmcnt(8) (confirm oldest 4 = tile t+1, never 0),
//     raw s_barrier + sched_barrier(0) fences, setprio(1) on MFMA cluster
//   - k-octet XOR swizzle kept (R13-verified: conflicts = 0):
//       stage: thread (srow,sq) loads global octet sq ^ ((srow>>1)&3)
//       read : frag slot q ^ ((r16>>1)&3), folded into per-lane base
//   - XCD swizzle rebuilt for 512 WGs: xcd = linear%8 owns 8 rowBands x
//     8 colBands (A panels L2-shared x8 within the XCD).

typedef short s16x8 __attribute__((ext_vector_type(8)));   // 8 bf16 in 4 VGPRs
typedef float f32x4 __attribute__((ext_vector_type(4)));

#define GK 9216
#define GN 1024
#define GI 1024
#define GM 8192

#define BK 32
#define NT 288               // GK/BK

#define BS_BLK 32768   // basis+silu: 8192*1024 threads (1 per x)
#define RP_BLK 4608    // repack   : 1024*1152 threads (8 cols each)

__device__ __forceinline__ void cp16(const __hip_bfloat16* g, __hip_bfloat16* l) {
  __builtin_amdgcn_global_load_lds((const __attribute__((address_space(1))) void*)g,
                                   (__attribute__((address_space(3))) void*)l, 16, 0, 0);
}

__device__ __forceinline__ uint32_t bfbits(float f) {   // RTNE bf16 bits, SSA only
  __hip_bfloat16 h = __float2bfloat16(f);
  unsigned short us;
  __builtin_memcpy(&us, &h, 2);
  return (uint32_t)us;
}

__device__ __forceinline__ void basis4(float xv, int& jj, float& w0, float& w1,
                                       float& w2, float& w3) {
  float t = fminf(1.f, fmaxf(-1.f, xv));
  float us = (t + 1.f) * 2.5f;          // (t - grid[3]) / h, grid[3]=-1, h=0.4
  int j = (int)us;
  if (j > 4) j = 4;                     // t==1.0 edge: matches reference exactly
  float u = us - (float)j;
  float u2 = u * u, u3 = u2 * u;
  float om = 1.f - u;
  jj = j;
  w0 = om * om * om * (1.f / 6.f);
  w1 = (3.f * u3 - 6.f * u2 + 4.f) * (1.f / 6.f);
  w2 = (-3.f * u3 + 3.f * u2 + 3.f * u + 1.f) * (1.f / 6.f);
  w3 = u3 * (1.f / 6.f);
}

// --- ONE dispatch: basis+silu (1 thread/x) + weight repack -----------------
__global__ void kan_prep_all(const float* __restrict__ x,
                             const float* __restrict__ baseW,
                             const float* __restrict__ splineW,
                             __hip_bfloat16* __restrict__ W2,
                             __hip_bfloat16* __restrict__ A) {
  int bid = blockIdx.x;
  if (bid < BS_BLK) {
    int t = bid * 256 + threadIdx.x;        // [0, 8192*1024)
    int b = t >> 10, i = t & 1023;
    float xv = x[t];

    // silu -> A[b, 8192+i], 2 B coalesced store
    float sl = xv / (1.f + __expf(-xv));
    A[(size_t)b * GK + 8192 + i] = __float2bfloat16(sl);

    // basis -> A[b, 8i..8i+7]: funnel-shift packed weights into window jj,
    // one dense 16 B store per lane (stride-16 across the wave)
    int jj; float w0, w1, w2, w3;
    basis4(xv, jj, w0, w1, w2, w3);
    uint64_t W64 = (uint64_t)(bfbits(w0) | (bfbits(w1) << 16)) |
                   ((uint64_t)(bfbits(w2) | (bfbits(w3) << 16)) << 32);
    int sh = jj * 16;                                  // 0,16,32,48,64
    uint64_t lo = (jj < 4) ? (W64 << sh) : 0ull;       // guard UB at sh=64
    uint64_t hi = (jj == 0) ? 0ull : (W64 >> (64 - sh));
    uint4 pk;
    pk.x = (uint32_t)lo;  pk.y = (uint32_t)(lo >> 32);
    pk.z = (uint32_t)hi;  pk.w = (uint32_t)(hi >> 32);
    *(uint4*)(A + (size_t)b * GK + (size_t)i * 8) = pk;
  } else {
    // repack: thread handles 8 cols (32 B fp32 in, 16 B bf16 out)
    int t = (bid - BS_BLK) * 256 + threadIdx.x;   // [0, 1024*1152)
    int o = t / 1152;
    int c = (t - o * 1152) * 8;
    const float* src = (c < 8192) ? (splineW + (size_t)o * 8192 + c)
                                  : (baseW + (size_t)o * GI + (c - 8192));
    float4 v0 = ((const float4*)src)[0];
    float4 v1 = ((const float4*)src)[1];
    uint4 pk;
    pk.x = bfbits(v0.x) | (bfbits(v0.y) << 16);
    pk.y = bfbits(v0.z) | (bfbits(v0.w) << 16);
    pk.z = bfbits(v1.x) | (bfbits(v1.y) << 16);
    pk.w = bfbits(v1.z) | (bfbits(v1.w) << 16);
    *(uint4*)(W2 + (size_t)o * GK + c) = pk;
  }
}

// --- R14 GEMM: 128x128 tile, 256 thr, ring-3 (48 KB), 2 blocks/CU ----------
__global__ __launch_bounds__(256, 2) void kan_gemm_dual(
    const __hip_bfloat16* __restrict__ A,   // (8192, 9216) bf16
    const __hip_bfloat16* __restrict__ B,   // (1024, 9216) bf16
    float* __restrict__ C) {                // (8192, 1024) fp32
  __shared__ __align__(16) __hip_bfloat16 As[3][128 * BK];   // 3 x 8 KB
  __shared__ __align__(16) __hip_bfloat16 Bs[3][128 * BK];   // 3 x 8 KB
  const int tid = threadIdx.x;
  const int lane = tid & 63;
  const int wave = tid >> 6;                 // 0..3
  const int wm = wave >> 1, wn = wave & 1;   // 2x2 waves, 64x64 out each

  // XCD swizzle over exactly 512 WGs: xcd = linear%8 owns 64 consecutive c's
  // = 8 rowBands x 8 colBands -> A panels L2-shared x8 within the XCD.
  const int linear = blockIdx.y * 8 + blockIdx.x;       // 0..511
  const int c = (linear & 7) * 64 + (linear >> 3);
  const int colBand = c & 7;                 // 0..7
  const int rowBand = c >> 3;                // 0..63
  const int blockRow = rowBand * 128;
  const int blockCol = colBand * 128;

  // staging: per cp16, 256 lanes x 16 B = 4 KB = 64 rows x 32 k, linear LDS.
  // k-octet XOR swizzle on the GLOBAL side (R13-verified, conflicts = 0):
  // thread (srow,sq) loads octet sq ^ ((srow>>1)&3); 64 B per 4-lane group
  // unchanged -> coalescing intact. Rows 64-127: (+64>>1)&3 == 0, same swz.
  const int srow = tid >> 2;                 // 0..63
  const int sq = tid & 3;
  const int ssw = sq ^ ((srow >> 1) & 3);    // swizzled source octet
  const __hip_bfloat16* aSrc = A + (size_t)(blockRow + srow) * GK + ssw * 8;
  const __hip_bfloat16* bSrc = B + (size_t)(blockCol + srow) * GK + ssw * 8;
  const int ldsOff = wave * 512;             // wave-uniform; HW adds lane*16 B

  // STAGE = 4 cp16: A rows 0-63, 64-127; B rows 0-63, 64-127 (4 KB each)
#define STAGE(T, BUF)                                             \
  do {                                                            \
    const __hip_bfloat16* ga = aSrc + (T) * BK;                   \
    const __hip_bfloat16* gb = bSrc + (T) * BK;                    \
    cp16(ga, As[BUF] + ldsOff);                                   \
    cp16(ga + 64 * GK, As[BUF] + ldsOff + 2048);                  \
    cp16(gb, Bs[BUF] + ldsOff);                                   \
    cp16(gb + 64 * GK, Bs[BUF] + ldsOff + 2048);                  \
  } while (0)

  const int q = lane >> 4, r16 = lane & 15;
  // frag read slot = q ^ ((row>>1)&3); wm*64/tm*16 shifts vanish mod 4
  // after >>1, so the swizzle folds into the per-lane constant base.
  const int qs = q ^ ((r16 >> 1) & 3);
  const int aBase = (wm * 64 + r16) * 4 + qs;   // s16x8 index; +tm*64
  const int bBase = (wn * 64 + r16) * 4 + qs;   // +tn*64

  f32x4 acc[4][4] = {};

  // prologue: 3 tiles in flight (12 loads), issue-order pinned per tile so
  // vmcnt(8) really confirms tile 0; then drain to 8.
  STAGE(0, 0);
  __builtin_amdgcn_sched_barrier(0);
  STAGE(1, 1);
  __builtin_amdgcn_sched_barrier(0);
  STAGE(2, 2);
  __builtin_amdgcn_sched_barrier(0);
  asm volatile("s_waitcnt vmcnt(8)" ::: "memory");
  __builtin_amdgcn_sched_barrier(0);
  __builtin_amdgcn_s_barrier();

  for (int t3 = 0; t3 < NT / 3; ++t3) {
#pragma unroll
    for (int u = 0; u < 3; ++u) {
      const int t = t3 * 3 + u;
      // tail guard: last 3 iters restage tile 0 (never read again) to keep
      // the vmcnt count identical without reading past the buffer.
      const int tp = (t + 3 < NT) ? (t + 3) : 0;
      __builtin_amdgcn_sched_barrier(0);
      // frag reads of buf u (tile t) — landed per prev iter's vmcnt+barrier
      const s16x8* Af = (const s16x8*)As[u];
      const s16x8* Bf = (const s16x8*)Bs[u];
      s16x8 af[4], bfg[4];
#pragma unroll
      for (int tm = 0; tm < 4; ++tm) af[tm] = Af[aBase + tm * 64];
#pragma unroll
      for (int tn = 0; tn < 4; ++tn) bfg[tn] = Bf[bBase + tn * 64];
      asm volatile("s_waitcnt lgkmcnt(0)" ::: "memory");
      __builtin_amdgcn_sched_barrier(0);
      __builtin_amdgcn_s_barrier();     // ALL waves done reading buf u
      __builtin_amdgcn_sched_barrier(0);
      STAGE(tp, u);                     // overwrite now safe (WAR ordered)
      __builtin_amdgcn_sched_barrier(0);
      __builtin_amdgcn_s_setprio(1);
#pragma unroll
      for (int tm = 0; tm < 4; ++tm)
#pragma unroll
        for (int tn = 0; tn < 4; ++tn)
          acc[tm][tn] = __builtin_amdgcn_mfma_f32_16x16x32_bf16(
              af[tm], bfg[tn], acc[tm][tn], 0, 0, 0);
      __builtin_amdgcn_s_setprio(0);
      // counted: 8 newest loads (tiles t+2, t+3) stay in flight; tile t+1
      // (oldest 4 of the 12) is confirmed. Never drain to 0 in the loop.
      asm volatile("s_waitcnt vmcnt(8)" ::: "memory");
      __builtin_amdgcn_sched_barrier(0);
      __builtin_amdgcn_s_barrier();
    }
  }
  // drain the tail prefetches before LDS goes away
  asm volatile("s_waitcnt vmcnt(0)" ::: "memory");

  // C/D layout: col = lane&15, row = (lane>>4)*4 + reg  [m89-verified]
  const int cRow0 = blockRow + wm * 64 + q * 4;
  const int cCol0 = blockCol + wn * 64 + r16;
#pragma unroll
  for (int tm = 0; tm < 4; ++tm)
#pragma unroll
    for (int tn = 0; tn < 4; ++tn) {
      int col = cCol0 + tn * 16;
      size_t base = (size_t)(cRow0 + tm * 16) * GN + col;
#pragma unroll
      for (int r = 0; r < 4; ++r)
        C[base + (size_t)r * GN] = acc[tm][tn][r];
    }
#undef STAGE
}

// --- emergency fallback if ws_size is too small ----------------------------
__global__ void kan_naive(const float* __restrict__ x,
                          const float* __restrict__ bw,
                          const float* __restrict__ sw,
                          float* __restrict__ out) {
  int o = blockIdx.x * 256 + threadIdx.x;
  int b = blockIdx.y;
  float acc = 0.f;
  for (int i = 0; i < GI; ++i) {
    float xv = x[(size_t)b * GI + i];
    float sl = xv / (1.f + __expf(-xv));
    acc += sl * bw[(size_t)o * GI + i];
    int jj; float w0, w1, w2, w3;
    basis4(xv, jj, w0, w1, w2, w3);
    const float* swr = sw + ((size_t)o * GI + i) * 8 + jj;
    acc += w0 * swr[0] + w1 * swr[1] + w2 * swr[2] + w3 * swr[3];
  }
  out[(size_t)b * GN + o] = acc;
}

extern "C" void kernel_launch(void* const* d_in, const int* in_sizes, int n_in,
                              void* d_out, int out_size, void* d_ws, size_t ws_size,
                              hipStream_t stream) {
  const float* x  = (const float*)d_in[0];   // (8192, 1024) fp32
  const float* bw = (const float*)d_in[1];   // (1024, 1024) fp32
  const float* sw = (const float*)d_in[2];   // (1024, 1024, 8) fp32
  float* out = (float*)d_out;                // (8192, 1024) fp32

  const size_t wBytes = (size_t)GK * GN * 2;   // 18.9 MB repacked weights
  const size_t aBytes = (size_t)GM * GK * 2;   // 151 MB activations

  if (ws_size < wBytes + aBytes) {
    kan_naive<<<dim3(GN / 256, GM), 256, 0, stream>>>(x, bw, sw, out);
    return;
  }

  __hip_bfloat16* W2 = (__hip_bfloat16*)d_ws;
  __hip_bfloat16* Abuf = W2 + (size_t)GK * GN;       // 16B-aligned

  kan_prep_all<<<BS_BLK + RP_BLK, 256, 0, stream>>>(x, bw, sw, W2, Abuf);
  kan_gemm_dual<<<dim3(GN / 128, GM / 128), 256, 0, stream>>>(Abuf, W2, out);
}